// Round 10
// baseline (352.446 us; speedup 1.0000x reference)
//
#include <hip/hip_runtime.h>

// Linear RNN scan: h_t = h_{t-1}@A + x_t@B ; y_t = h_t@C
// B=8, S=4096, IN=STATE=OUT=256.
// MFMA 16x16x32 f16, 2-term split (hi + 2048*lo), f32 accumulate.
// Swapped operands: out^T = M^T @ in^T (frags = A-operand, LDS tile = B-operand).
// Slice-linear LDS: per slice s a 1024B region, slot ((ak<<4)|row)^s -> conflict-free.
// FUSED sweeps, register-budgeted:
//   scan_up   : u=x@B (B-frags STREAMED from L2) + local scan (A-frags RESIDENT) -> U,E
//   scan_down : scan from entry (A resident) + y=h@C (C-frags STREAMED) -> y
// NT hints on streams (x,U,y) so frag arrays stay L2-resident.
// Spine: collect (A^8) / top (A^128) / scan2 (A^8) on mfma_rscan (plain caching).

#define SEQ    4096
#define NBATCH 8
#define ND     256
#define CHUNK  8
#define NCHUNK 512
#define GSZ    16
#define NGRP   32
#define LOSC   2048.0f
#define LOINV  (1.0f/2048.0f)

typedef _Float16 fp16_t;
typedef __attribute__((ext_vector_type(8))) _Float16 f16x8;
typedef __attribute__((ext_vector_type(4))) _Float16 f16x4;
typedef __attribute__((ext_vector_type(4))) float f32x4;

__device__ __forceinline__ f32x4 ldnt4(const float* p) {
  return __builtin_nontemporal_load((const f32x4*)p);
}
__device__ __forceinline__ void stnt4(float* p, f32x4 v) {
  __builtin_nontemporal_store(v, (f32x4*)p);
}

// ---------- pack A,B,C into frag arrays (hi/lo f16) ----------
// frag linear index: ((tile*8 + slice)*64 + lane)*8 + j
// value = M[k][n], k = slice*32 + (lane>>4)*8 + j, n = tile*16 + (lane&15)
__global__ __launch_bounds__(64) void prep_frags3(
    const float* __restrict__ A, const float* __restrict__ B,
    const float* __restrict__ C,
    fp16_t* __restrict__ fAh, fp16_t* __restrict__ fAl,
    fp16_t* __restrict__ fBh, fp16_t* __restrict__ fBl,
    fp16_t* __restrict__ fCh, fp16_t* __restrict__ fCl) {
  const int which = blockIdx.x >> 7;
  const int blk   = blockIdx.x & 127;
  const float* M = (which == 0) ? A : (which == 1) ? B : C;
  fp16_t* hi = (which == 0) ? fAh : (which == 1) ? fBh : fCh;
  fp16_t* lo = (which == 0) ? fAl : (which == 1) ? fBl : fCl;
  const int lane = threadIdx.x;
  const int tile = blk >> 3, slice = blk & 7;
  const int n  = tile * 16 + (lane & 15);
  const int k0 = slice * 32 + (lane >> 4) * 8;
  f16x8 vh, vl;
  #pragma unroll
  for (int j = 0; j < 8; ++j) {
    const float v = M[(size_t)(k0 + j) * ND + n];
    const fp16_t h = (fp16_t)v;
    vh[j] = h;
    vl[j] = (fp16_t)((v - (float)h) * LOSC);
  }
  const size_t fo = ((size_t)blk * 64 + lane) * 8;
  *(f16x8*)&hi[fo] = vh;
  *(f16x8*)&lo[fo] = vl;
}

// ---------- pack A8, A128 into frag arrays ----------
__global__ __launch_bounds__(64) void prep_frags2(
    const float* __restrict__ M0, const float* __restrict__ M1,
    fp16_t* __restrict__ h0p, fp16_t* __restrict__ l0p,
    fp16_t* __restrict__ h1p, fp16_t* __restrict__ l1p) {
  const int which = blockIdx.x >> 7;
  const int blk   = blockIdx.x & 127;
  const float* M = (which == 0) ? M0 : M1;
  fp16_t* hi = (which == 0) ? h0p : h1p;
  fp16_t* lo = (which == 0) ? l0p : l1p;
  const int lane = threadIdx.x;
  const int tile = blk >> 3, slice = blk & 7;
  const int n  = tile * 16 + (lane & 15);
  const int k0 = slice * 32 + (lane >> 4) * 8;
  f16x8 vh, vl;
  #pragma unroll
  for (int j = 0; j < 8; ++j) {
    const float v = M[(size_t)(k0 + j) * ND + n];
    const fp16_t h = (fp16_t)v;
    vh[j] = h;
    vl[j] = (fp16_t)((v - (float)h) * LOSC);
  }
  const size_t fo = ((size_t)blk * 64 + lane) * 8;
  *(f16x8*)&hi[fo] = vh;
  *(f16x8*)&lo[fo] = vl;
}

// ---------- fused up-sweep: u = x@B (B streamed); local scan (A resident) ----------
__global__ __launch_bounds__(1024, 4) void scan_up(
    const fp16_t* __restrict__ fAh, const fp16_t* __restrict__ fAl,
    const fp16_t* __restrict__ fBh, const fp16_t* __restrict__ fBl,
    const float* __restrict__ x, float* __restrict__ U, float* __restrict__ E) {
  const int c2   = blockIdx.x;        // chunks 2*c2, 2*c2+1
  const int tid  = threadIdx.x;
  const int lane = tid & 63;
  const int w    = tid >> 6;
  const int br   = lane & 15;
  const int akg  = lane >> 4;

  __shared__ fp16_t xH[2][8 * 512], xL[2][8 * 512];
  __shared__ fp16_t hH[2][8 * 512], hL[2][8 * 512];

  // staging geometry: thread loads 4 f32 of one (c,b) row per step
  const int srow  = tid >> 6;                 // 0..15
  const int scol  = (tid & 63) * 4;           // 0..252
  const int ss    = (tid >> 3) & 7;
  const int sak   = (tid >> 1) & 3;
  const int shalf = tid & 1;
  const int soff  = (ss << 10) + ((((sak << 4) | srow) ^ ss) << 4) + shalf * 8;
  const int sb    = srow & 7;
  const int sc    = 2 * c2 + (srow >> 3);
  const float* xsrc = &x[((size_t)sb * SEQ + (size_t)sc * CHUNK) * ND + scol];

  // resident A^T frags only (64 VGPR)
  f16x8 AH[8], AL[8];
  #pragma unroll
  for (int s = 0; s < 8; ++s) {
    const size_t fo = (((size_t)w * 8 + s) * 64 + lane) * 8;
    AH[s] = *(const f16x8*)&fAh[fo];
    AL[s] = *(const f16x8*)&fAl[fo];
  }

  // stage x_0 into xbuf 0
  {
    const f32x4 xv = ldnt4(xsrc);
    f16x4 vh, vl;
    #pragma unroll
    for (int r = 0; r < 4; ++r) {
      const fp16_t h = (fp16_t)xv[r];
      vh[r] = h;
      vl[r] = (fp16_t)((xv[r] - (float)h) * LOSC);
    }
    *(f16x4*)((char*)xH[0] + soff) = vh;
    *(f16x4*)((char*)xL[0] + soff) = vl;
  }
  __syncthreads();

  // this lane's C-rows: chunk sq, batch b, 4 state cols
  const int sq   = 2 * c2 + (br >> 3);
  const int b    = br & 7;
  const int col0 = w * 16 + akg * 4;
  const int rbase = (akg << 4) | br;
  const int sw    = col0 >> 5;
  const int akr   = (col0 >> 3) & 3;
  const int wroff = (sw << 10) + ((((akr << 4) | br) ^ sw) << 4) + (col0 & 7) * 2;

  f32x4 res;
  int q = 0, p = 0;
  #pragma unroll 1
  for (int j = 0; j < CHUNK; ++j) {
    f32x4 xn;
    if (j + 1 < CHUNK) xn = ldnt4(xsrc + (size_t)(j + 1) * ND);
    // B-chain: u = x_j @ B  (B-frags streamed from L2)
    f32x4 am = (f32x4)0.0f, al = (f32x4)0.0f;
    {
      const char* rH = (const char*)xH[q];
      const char* rL = (const char*)xL[q];
      #pragma unroll
      for (int s = 0; s < 8; ++s) {
        const int ro = (s << 10) + (((rbase) ^ s) << 4);
        const f16x8 bh = *(const f16x8*)(rH + ro);
        const f16x8 bl = *(const f16x8*)(rL + ro);
        const size_t fo = (((size_t)w * 8 + s) * 64 + lane) * 8;
        const f16x8 BHs = *(const f16x8*)&fBh[fo];
        const f16x8 BLs = *(const f16x8*)&fBl[fo];
        am = __builtin_amdgcn_mfma_f32_16x16x32_f16(BHs, bh, am, 0, 0, 0);
        al = __builtin_amdgcn_mfma_f32_16x16x32_f16(BLs, bh, al, 0, 0, 0);
        al = __builtin_amdgcn_mfma_f32_16x16x32_f16(BHs, bl, al, 0, 0, 0);
      }
    }
    // snapshot u -> U (pass-1 input), NT
    {
      f32x4 o;
      #pragma unroll
      for (int r = 0; r < 4; ++r) o[r] = am[r] + al[r] * LOINV;
      stnt4(&U[((size_t)(sq * CHUNK + j) * NBATCH + b) * ND + col0], o);
    }
    // A-chain: + h_{j-1} @ A  (h_{-1}=0), resident frags
    if (j > 0) {
      const char* rH = (const char*)hH[p];
      const char* rL = (const char*)hL[p];
      #pragma unroll
      for (int s = 0; s < 8; ++s) {
        const int ro = (s << 10) + (((rbase) ^ s) << 4);
        const f16x8 bh = *(const f16x8*)(rH + ro);
        const f16x8 bl = *(const f16x8*)(rL + ro);
        am = __builtin_amdgcn_mfma_f32_16x16x32_f16(AH[s], bh, am, 0, 0, 0);
        al = __builtin_amdgcn_mfma_f32_16x16x32_f16(AL[s], bh, al, 0, 0, 0);
        al = __builtin_amdgcn_mfma_f32_16x16x32_f16(AH[s], bl, al, 0, 0, 0);
      }
    }
    #pragma unroll
    for (int r = 0; r < 4; ++r) res[r] = am[r] + al[r] * LOINV;
    // write h_j -> hbuf[p^1]
    {
      f16x4 vh, vl;
      #pragma unroll
      for (int r = 0; r < 4; ++r) {
        const fp16_t hh = (fp16_t)res[r];
        vh[r] = hh;
        vl[r] = (fp16_t)((res[r] - (float)hh) * LOSC);
      }
      *(f16x4*)((char*)hH[p ^ 1] + wroff) = vh;
      *(f16x4*)((char*)hL[p ^ 1] + wroff) = vl;
    }
    // write x_{j+1} -> xbuf[q^1]
    if (j + 1 < CHUNK) {
      f16x4 vh, vl;
      #pragma unroll
      for (int r = 0; r < 4; ++r) {
        const fp16_t h = (fp16_t)xn[r];
        vh[r] = h;
        vl[r] = (fp16_t)((xn[r] - (float)h) * LOSC);
      }
      *(f16x4*)((char*)xH[q ^ 1] + soff) = vh;
      *(f16x4*)((char*)xL[q ^ 1] + soff) = vl;
    }
    q ^= 1; p ^= 1;
    __syncthreads();
  }
  // chunk-end state (normal store; read soon by collect)
  *(f32x4*)&E[((size_t)sq * NBATCH + b) * ND + col0] = res;
}

// ---------- fused down-sweep: scan from entry (A resident); y=h@C (C streamed) ----------
__global__ __launch_bounds__(1024, 4) void scan_down(
    const fp16_t* __restrict__ fAh, const fp16_t* __restrict__ fAl,
    const fp16_t* __restrict__ fCh, const fp16_t* __restrict__ fCl,
    const float* __restrict__ Hc, const float* __restrict__ U,
    float* __restrict__ y) {
  const int c2   = blockIdx.x;
  const int tid  = threadIdx.x;
  const int lane = tid & 63;
  const int w    = tid >> 6;
  const int br   = lane & 15;
  const int akg  = lane >> 4;

  __shared__ fp16_t hH[2][8 * 512], hL[2][8 * 512];

  // init hbuf[0] = entry states Hc (normal loads; small, L2-hot)
  {
    const int srow  = tid >> 6;
    const int scol  = (tid & 63) * 4;
    const int ss    = (tid >> 3) & 7;
    const int sak   = (tid >> 1) & 3;
    const int shalf = tid & 1;
    const int soff  = (ss << 10) + ((((sak << 4) | srow) ^ ss) << 4) + shalf * 8;
    const int sc = 2 * c2 + (srow >> 3);
    const int sb = srow & 7;
    const f32x4 v = *(const f32x4*)&Hc[((size_t)sc * NBATCH + sb) * ND + scol];
    f16x4 vh, vl;
    #pragma unroll
    for (int r = 0; r < 4; ++r) {
      const fp16_t h = (fp16_t)v[r];
      vh[r] = h;
      vl[r] = (fp16_t)((v[r] - (float)h) * LOSC);
    }
    *(f16x4*)((char*)hH[0] + soff) = vh;
    *(f16x4*)((char*)hL[0] + soff) = vl;
  }

  // resident A^T frags only (64 VGPR)
  f16x8 AH[8], AL[8];
  #pragma unroll
  for (int s = 0; s < 8; ++s) {
    const size_t fo = (((size_t)w * 8 + s) * 64 + lane) * 8;
    AH[s] = *(const f16x8*)&fAh[fo];
    AL[s] = *(const f16x8*)&fAl[fo];
  }
  __syncthreads();

  const int sq   = 2 * c2 + (br >> 3);
  const int b    = br & 7;
  const int col0 = w * 16 + akg * 4;
  const int rbase = (akg << 4) | br;
  const int sw    = col0 >> 5;
  const int akr   = (col0 >> 3) & 3;
  const int wroff = (sw << 10) + ((((akr << 4) | br) ^ sw) << 4) + (col0 & 7) * 2;
  const size_t t0 = (size_t)sq * CHUNK;

  f32x4 uv = ldnt4(&U[(t0 * NBATCH + b) * ND + col0]);
  f32x4 uvn;
  f32x4 res;
  int p = 0;

  // j = 0: h_0 = entry@A + u_0  (no y yet)
  {
    uvn = ldnt4(&U[((t0 + 1) * NBATCH + b) * ND + col0]);
    f32x4 am = uv, al = (f32x4)0.0f;
    const char* rH = (const char*)hH[0];
    const char* rL = (const char*)hL[0];
    #pragma unroll
    for (int s = 0; s < 8; ++s) {
      const int ro = (s << 10) + (((rbase) ^ s) << 4);
      const f16x8 bh = *(const f16x8*)(rH + ro);
      const f16x8 bl = *(const f16x8*)(rL + ro);
      am = __builtin_amdgcn_mfma_f32_16x16x32_f16(AH[s], bh, am, 0, 0, 0);
      al = __builtin_amdgcn_mfma_f32_16x16x32_f16(AL[s], bh, al, 0, 0, 0);
      al = __builtin_amdgcn_mfma_f32_16x16x32_f16(AH[s], bl, al, 0, 0, 0);
    }
    #pragma unroll
    for (int r = 0; r < 4; ++r) res[r] = am[r] + al[r] * LOINV;
    f16x4 vh, vl;
    #pragma unroll
    for (int r = 0; r < 4; ++r) {
      const fp16_t hh = (fp16_t)res[r];
      vh[r] = hh;
      vl[r] = (fp16_t)((res[r] - (float)hh) * LOSC);
    }
    *(f16x4*)((char*)hH[1] + wroff) = vh;
    *(f16x4*)((char*)hL[1] + wroff) = vl;
    uv = uvn;
    p = 1;
    __syncthreads();
  }

  // j = 1..7: h_j = h_{j-1}@A + u_j ; y_{j-1} = h_{j-1}@C (C-frags streamed)
  #pragma unroll 1
  for (int j = 1; j < CHUNK; ++j) {
    if (j + 1 < CHUNK)
      uvn = ldnt4(&U[((t0 + j + 1) * NBATCH + b) * ND + col0]);
    f32x4 am = uv, al = (f32x4)0.0f;
    f32x4 cm = (f32x4)0.0f, cl = (f32x4)0.0f;
    const char* rH = (const char*)hH[p];
    const char* rL = (const char*)hL[p];
    #pragma unroll
    for (int s = 0; s < 8; ++s) {
      const int ro = (s << 10) + (((rbase) ^ s) << 4);
      const f16x8 bh = *(const f16x8*)(rH + ro);
      const f16x8 bl = *(const f16x8*)(rL + ro);
      const size_t fo = (((size_t)w * 8 + s) * 64 + lane) * 8;
      const f16x8 CHs = *(const f16x8*)&fCh[fo];
      const f16x8 CLs = *(const f16x8*)&fCl[fo];
      am = __builtin_amdgcn_mfma_f32_16x16x32_f16(AH[s], bh, am, 0, 0, 0);
      al = __builtin_amdgcn_mfma_f32_16x16x32_f16(AL[s], bh, al, 0, 0, 0);
      al = __builtin_amdgcn_mfma_f32_16x16x32_f16(AH[s], bl, al, 0, 0, 0);
      cm = __builtin_amdgcn_mfma_f32_16x16x32_f16(CHs, bh, cm, 0, 0, 0);
      cl = __builtin_amdgcn_mfma_f32_16x16x32_f16(CLs, bh, cl, 0, 0, 0);
      cl = __builtin_amdgcn_mfma_f32_16x16x32_f16(CHs, bl, cl, 0, 0, 0);
    }
    #pragma unroll
    for (int r = 0; r < 4; ++r) res[r] = am[r] + al[r] * LOINV;
    {
      f16x4 vh, vl;
      #pragma unroll
      for (int r = 0; r < 4; ++r) {
        const fp16_t hh = (fp16_t)res[r];
        vh[r] = hh;
        vl[r] = (fp16_t)((res[r] - (float)hh) * LOSC);
      }
      *(f16x4*)((char*)hH[p ^ 1] + wroff) = vh;
      *(f16x4*)((char*)hL[p ^ 1] + wroff) = vl;
    }
    {
      f32x4 o;
      #pragma unroll
      for (int r = 0; r < 4; ++r) o[r] = cm[r] + cl[r] * LOINV;
      stnt4(&y[((size_t)b * SEQ + t0 + j - 1) * ND + col0], o);
    }
    uv = uvn;
    p ^= 1;
    __syncthreads();
  }

  // epilogue: y_7 = h_7 @ C (C streamed)
  {
    f32x4 cm = (f32x4)0.0f, cl = (f32x4)0.0f;
    const char* rH = (const char*)hH[p];
    const char* rL = (const char*)hL[p];
    #pragma unroll
    for (int s = 0; s < 8; ++s) {
      const int ro = (s << 10) + (((rbase) ^ s) << 4);
      const f16x8 bh = *(const f16x8*)(rH + ro);
      const f16x8 bl = *(const f16x8*)(rL + ro);
      const size_t fo = (((size_t)w * 8 + s) * 64 + lane) * 8;
      const f16x8 CHs = *(const f16x8*)&fCh[fo];
      const f16x8 CLs = *(const f16x8*)&fCl[fo];
      cm = __builtin_amdgcn_mfma_f32_16x16x32_f16(CHs, bh, cm, 0, 0, 0);
      cl = __builtin_amdgcn_mfma_f32_16x16x32_f16(CLs, bh, cl, 0, 0, 0);
      cl = __builtin_amdgcn_mfma_f32_16x16x32_f16(CHs, bl, cl, 0, 0, 0);
    }
    f32x4 o;
    #pragma unroll
    for (int r = 0; r < 4; ++r) o[r] = cm[r] + cl[r] * LOINV;
    stnt4(&y[((size_t)b * SEQ + t0 + CHUNK - 1) * ND + col0], o);
  }
}

// ---------- unified MFMA recurrence kernel (spine levels, plain caching) ----------
__global__ __launch_bounds__(1024, 4) void mfma_rscan(
    const fp16_t* __restrict__ Mh, const fp16_t* __restrict__ Ml,
    const float* __restrict__ Init,
    const float* In,
    float* OutEach,
    float* __restrict__ OutFinal,
    int nupd, int gstride, int nseq, int init_bcast, int entry_mode) {
  const int seq0 = blockIdx.x * 2;
  const int tid  = threadIdx.x;
  const int lane = tid & 63;
  const int w    = tid >> 6;
  const int br   = lane & 15;
  const int akg  = lane >> 4;

  __shared__ fp16_t hH[2][8 * 512];
  __shared__ fp16_t hL[2][8 * 512];

  {
    const int task = tid >> 1;
    const int half = tid & 1;
    const int row  = task & 15;
    const int s    = (task >> 4) & 7;
    const int ak   = task >> 7;
    const int sq = seq0 + (row >> 3);
    const int b  = row & 7;
    const int c0 = s * 32 + ak * 8 + half * 4;
    f32x4 v = (f32x4)0.0f;
    if (Init != nullptr && sq < nseq) {
      const size_t off = init_bcast ? (size_t)c0
                                    : ((size_t)sq * NBATCH + b) * ND + c0;
      v = *(const f32x4*)&Init[off];
      if (entry_mode && OutEach != nullptr)
        *(f32x4*)&OutEach[((size_t)sq * gstride * NBATCH + b) * ND + c0] = v;
    }
    f16x4 vh, vl;
    #pragma unroll
    for (int j = 0; j < 4; ++j) {
      const fp16_t h = (fp16_t)v[j];
      vh[j] = h;
      vl[j] = (fp16_t)((v[j] - (float)h) * LOSC);
    }
    const int off = (s << 10) + ((((ak << 4) | row) ^ s) << 4) + half * 8;
    *(f16x4*)((char*)hH[0] + off) = vh;
    *(f16x4*)((char*)hL[0] + off) = vl;
  }

  f16x8 AH[8], AL[8];
  #pragma unroll
  for (int s = 0; s < 8; ++s) {
    const size_t fo = (((size_t)w * 8 + s) * 64 + lane) * 8;
    AH[s] = *(const f16x8*)&Mh[fo];
    AL[s] = *(const f16x8*)&Ml[fo];
  }
  __syncthreads();

  const int sq   = seq0 + (br >> 3);
  const int b    = br & 7;
  const bool live = (sq < nseq);
  const int sqc  = live ? sq : (nseq - 1);
  const int col0 = w * 16 + akg * 4;
  const int rbase = (akg << 4) | br;
  const int sw   = col0 >> 5;
  const int akr  = (col0 >> 3) & 3;
  const int wroff = (sw << 10) + ((((akr << 4) | br) ^ sw) << 4) + (col0 & 7) * 2;

  f32x4 uv = *(const f32x4*)&In[((size_t)(sqc * gstride) * NBATCH + b) * ND + col0];
  f32x4 uvn;
  f32x4 res;
  int p = 0;
  for (int j = 0; j < nupd; ++j) {
    if (j + 1 < nupd)
      uvn = *(const f32x4*)&In[((size_t)(sqc * gstride + j + 1) * NBATCH + b) * ND + col0];
    const char* rH = (const char*)hH[p];
    const char* rL = (const char*)hL[p];
    f32x4 accm = uv, acclA = (f32x4)0.0f, acclB = (f32x4)0.0f;
    #pragma unroll
    for (int s = 0; s < 8; ++s) {
      const int ro = (s << 10) + (((rbase) ^ s) << 4);
      const f16x8 bh = *(const f16x8*)(rH + ro);
      const f16x8 bl = *(const f16x8*)(rL + ro);
      accm  = __builtin_amdgcn_mfma_f32_16x16x32_f16(AH[s], bh, accm,  0, 0, 0);
      acclA = __builtin_amdgcn_mfma_f32_16x16x32_f16(AL[s], bh, acclA, 0, 0, 0);
      acclB = __builtin_amdgcn_mfma_f32_16x16x32_f16(AH[s], bl, acclB, 0, 0, 0);
    }
    #pragma unroll
    for (int r = 0; r < 4; ++r) res[r] = accm[r] + (acclA[r] + acclB[r]) * LOINV;
    {
      f16x4 vh, vl;
      #pragma unroll
      for (int r = 0; r < 4; ++r) {
        const fp16_t hh = (fp16_t)res[r];
        vh[r] = hh;
        vl[r] = (fp16_t)((res[r] - (float)hh) * LOSC);
      }
      *(f16x4*)((char*)hH[p ^ 1] + wroff) = vh;
      *(f16x4*)((char*)hL[p ^ 1] + wroff) = vl;
    }
    if (OutEach != nullptr && live) {
      const size_t pos = entry_mode ? (size_t)(sq * gstride + j + 1)
                                    : (size_t)(sq * gstride + j);
      *(f32x4*)&OutEach[(pos * NBATCH + b) * ND + col0] = res;
    }
    uv = uvn;
    p ^= 1;
    __syncthreads();
  }

  if (OutFinal != nullptr && live)
    *(f32x4*)&OutFinal[((size_t)sq * NBATCH + b) * ND + col0] = res;
}

// ---------- dense 256x256 f32 GEMM (A-power chain) ----------
__global__ __launch_bounds__(256) void gemm256(const float* __restrict__ X,
                                               const float* __restrict__ Y,
                                               float* __restrict__ Out) {
  const int m0 = blockIdx.x * 4;
  const int n  = threadIdx.x;
  __shared__ float Xs[ND][4];
  #pragma unroll
  for (int r = 0; r < 4; ++r) Xs[n][r] = X[(m0 + r) * ND + n];
  __syncthreads();
  float a0 = 0.f, a1 = 0.f, a2 = 0.f, a3 = 0.f;
  #pragma unroll 8
  for (int k = 0; k < ND; ++k) {
    const float yv = Y[k * ND + n];
    const float4 xv = *(const float4*)&Xs[k][0];
    a0 = fmaf(xv.x, yv, a0);
    a1 = fmaf(xv.y, yv, a1);
    a2 = fmaf(xv.z, yv, a2);
    a3 = fmaf(xv.w, yv, a3);
  }
  Out[(m0 + 0) * ND + n] = a0;
  Out[(m0 + 1) * ND + n] = a1;
  Out[(m0 + 2) * ND + n] = a2;
  Out[(m0 + 3) * ND + n] = a3;
}

extern "C" void kernel_launch(void* const* d_in, const int* in_sizes, int n_in,
                              void* d_out, int out_size, void* d_ws, size_t ws_size,
                              hipStream_t stream) {
  const float* x  = (const float*)d_in[0];
  const float* A  = (const float*)d_in[1];
  const float* Bm = (const float*)d_in[2];
  const float* Cm = (const float*)d_in[3];
  const float* h0 = (const float*)d_in[4];
  float* y = (float*)d_out;

  float* U    = (float*)d_ws;                        // 8,388,608
  float* t0   = U + (size_t)SEQ * NBATCH * ND;       // 65,536 (reused for A8 frags)
  float* t1   = t0 + ND * ND;                        // 65,536 (reused for A128 frags)
  float* A8   = t1 + ND * ND;
  float* A128 = A8 + ND * ND;
  float* E    = A128 + ND * ND;                      // 1,048,576
  float* Sg   = E + (size_t)NCHUNK * NBATCH * ND;    // 65,536
  float* G    = Sg + (size_t)NGRP * NBATCH * ND;     // 65,536
  float* Hc   = G + (size_t)NGRP * NBATCH * ND;      // 1,048,576
  fp16_t* fA_hi = (fp16_t*)(Hc + (size_t)NCHUNK * NBATCH * ND);
  fp16_t* fA_lo = fA_hi + ND * ND;
  fp16_t* fB_hi = fA_lo + ND * ND;
  fp16_t* fB_lo = fB_hi + ND * ND;
  fp16_t* fC_hi = fB_lo + ND * ND;
  fp16_t* fC_lo = fC_hi + ND * ND;
  fp16_t* fA8_hi   = (fp16_t*)t0;
  fp16_t* fA8_lo   = fA8_hi + ND * ND;
  fp16_t* fA128_hi = (fp16_t*)t1;
  fp16_t* fA128_lo = fA128_hi + ND * ND;

  // pack A,B,C into fragment arrays
  prep_frags3<<<384, 64, 0, stream>>>(A, Bm, Cm, fA_hi, fA_lo, fB_hi, fB_lo,
                                      fC_hi, fC_lo);

  // A powers (f32): A^8, A^128  (t0/t1 scratch, then freed)
  gemm256<<<64, 256, 0, stream>>>(A,  A,  t0);       // A^2
  gemm256<<<64, 256, 0, stream>>>(t0, t0, t1);       // A^4
  gemm256<<<64, 256, 0, stream>>>(t1, t1, A8);       // A^8
  gemm256<<<64, 256, 0, stream>>>(A8, A8, t0);       // A^16
  gemm256<<<64, 256, 0, stream>>>(t0, t0, t1);       // A^32
  gemm256<<<64, 256, 0, stream>>>(t1, t1, t0);       // A^64
  gemm256<<<64, 256, 0, stream>>>(t0, t0, A128);     // A^128

  // pack A8/A128 into frags (t0/t1 storage reuse)
  prep_frags2<<<256, 64, 0, stream>>>(A8, A128, fA8_hi, fA8_lo,
                                      fA128_hi, fA128_lo);

  // fused up-sweep: u = x@B + chunk local scan -> U, E
  scan_up<<<NCHUNK / 2, 1024, 0, stream>>>(fA_hi, fA_lo, fB_hi, fB_lo, x, U, E);

  // group collect: Sg[g] = scan(0; E over group g) with A^8
  mfma_rscan<<<NGRP / 2, 1024, 0, stream>>>(fA8_hi, fA8_lo, nullptr, E,
                                            nullptr, Sg, GSZ, GSZ, NGRP, 0, 0);

  // top scan: G[0]=h0; G[g+1] = G[g]@A128 + Sg[g]
  mfma_rscan<<<1, 1024, 0, stream>>>(fA128_hi, fA128_lo, h0, Sg,
                                     G, nullptr, NGRP - 1, NGRP, 1, 1, 1);

  // group entries: Hc[g*GSZ]=G[g]; Hc[c+1] = Hc[c]@A8 + E[c]
  mfma_rscan<<<NGRP / 2, 1024, 0, stream>>>(fA8_hi, fA8_lo, G, E,
                                            Hc, nullptr, GSZ - 1, GSZ, NGRP,
                                            0, 1);

  // fused down-sweep: chunk scan from entry + y = h@C
  scan_down<<<NCHUNK / 2, 1024, 0, stream>>>(fA_hi, fA_lo, fC_hi, fC_lo,
                                             Hc, U, y);
}

// Round 11
// 269.484 us; speedup vs baseline: 1.3079x; 1.3079x over previous
//
#include <hip/hip_runtime.h>

// Linear RNN scan: h_t = h_{t-1}@A + x_t@B ; y_t = h_t@C
// B=8, S=4096, IN=STATE=OUT=256.
// MFMA 16x16x32 f16, 2-term split (hi + 2048*lo), f32 accumulate.
// Swapped operands: out^T = M^T @ in^T (frags = A-operand, LDS tile = B-operand).
// Slice-linear LDS: per slice s a 1024B region, slot ((ak<<4)|row)^s -> conflict-free.
// UNFUSED round-7 structure. NEW: inline-asm PIN on resident frags
// (asm volatile "+v") so the compiler cannot rematerialize the frag loads
// inside the step loop -- forces true VGPR residency (VGPR ~104-115).

#define SEQ    4096
#define NBATCH 8
#define ND     256
#define CHUNK  8
#define NCHUNK 512
#define GSZ    16
#define NGRP   32
#define LOSC   2048.0f
#define LOINV  (1.0f/2048.0f)

typedef _Float16 fp16_t;
typedef __attribute__((ext_vector_type(8))) _Float16 f16x8;
typedef __attribute__((ext_vector_type(4))) _Float16 f16x4;
typedef __attribute__((ext_vector_type(4))) float f32x4;

// Force a loaded fragment to stay materialized in VGPRs: the asm is opaque,
// so the compiler cannot re-derive (re-load) the value inside loops.
__device__ __forceinline__ void pin(f16x8& x) { asm volatile("" : "+v"(x)); }

// ---------- pack A,B,C into frag arrays (hi/lo f16) ----------
// frag linear index: ((tile*8 + slice)*64 + lane)*8 + j
// value = M[k][n], k = slice*32 + (lane>>4)*8 + j, n = tile*16 + (lane&15)
__global__ __launch_bounds__(64) void prep_frags3(
    const float* __restrict__ A, const float* __restrict__ B,
    const float* __restrict__ C,
    fp16_t* __restrict__ fAh, fp16_t* __restrict__ fAl,
    fp16_t* __restrict__ fBh, fp16_t* __restrict__ fBl,
    fp16_t* __restrict__ fCh, fp16_t* __restrict__ fCl) {
  const int which = blockIdx.x >> 7;
  const int blk   = blockIdx.x & 127;
  const float* M = (which == 0) ? A : (which == 1) ? B : C;
  fp16_t* hi = (which == 0) ? fAh : (which == 1) ? fBh : fCh;
  fp16_t* lo = (which == 0) ? fAl : (which == 1) ? fBl : fCl;
  const int lane = threadIdx.x;
  const int tile = blk >> 3, slice = blk & 7;
  const int n  = tile * 16 + (lane & 15);
  const int k0 = slice * 32 + (lane >> 4) * 8;
  f16x8 vh, vl;
  #pragma unroll
  for (int j = 0; j < 8; ++j) {
    const float v = M[(size_t)(k0 + j) * ND + n];
    const fp16_t h = (fp16_t)v;
    vh[j] = h;
    vl[j] = (fp16_t)((v - (float)h) * LOSC);
  }
  const size_t fo = ((size_t)blk * 64 + lane) * 8;
  *(f16x8*)&hi[fo] = vh;
  *(f16x8*)&lo[fo] = vl;
}

// ---------- pack A8, A128 into frag arrays ----------
__global__ __launch_bounds__(64) void prep_frags2(
    const float* __restrict__ M0, const float* __restrict__ M1,
    fp16_t* __restrict__ h0p, fp16_t* __restrict__ l0p,
    fp16_t* __restrict__ h1p, fp16_t* __restrict__ l1p) {
  const int which = blockIdx.x >> 7;
  const int blk   = blockIdx.x & 127;
  const float* M = (which == 0) ? M0 : M1;
  fp16_t* hi = (which == 0) ? h0p : h1p;
  fp16_t* lo = (which == 0) ? l0p : l1p;
  const int lane = threadIdx.x;
  const int tile = blk >> 3, slice = blk & 7;
  const int n  = tile * 16 + (lane & 15);
  const int k0 = slice * 32 + (lane >> 4) * 8;
  f16x8 vh, vl;
  #pragma unroll
  for (int j = 0; j < 8; ++j) {
    const float v = M[(size_t)(k0 + j) * ND + n];
    const fp16_t h = (fp16_t)v;
    vh[j] = h;
    vl[j] = (fp16_t)((v - (float)h) * LOSC);
  }
  const size_t fo = ((size_t)blk * 64 + lane) * 8;
  *(f16x8*)&hi[fo] = vh;
  *(f16x8*)&lo[fo] = vl;
}

// ---------- MFMA GEMM: Out[m][:] = X[m][:] @ M,  m = s*8+b, M-block = 64 ----------
// mode 0 (xb): X rows remapped from x[b][s][:];  mode 1 (y): Out remapped to y[b][s][:]
__global__ __launch_bounds__(1024, 2) void mfma_gemm(const float* __restrict__ X,
                                                     const fp16_t* __restrict__ Mhi,
                                                     const fp16_t* __restrict__ Mlo,
                                                     float* __restrict__ Out,
                                                     int mode) {
  const int m0   = blockIdx.x * 64;
  const int tid  = threadIdx.x;
  const int lane = tid & 63;
  const int w    = tid >> 6;          // 16 waves, M-col tile w
  const int br   = lane & 15;
  const int akg  = lane >> 4;

  __shared__ fp16_t Xh[32 * 512];     // 32 regions x 1024B (slice-linear)
  __shared__ fp16_t Xl[32 * 512];
  char* Xhb = (char*)Xh;
  char* Xlb = (char*)Xl;

  // stage 64 rows of X -> hi/lo, slice-linear layout (fully coalesced global)
  #pragma unroll
  for (int pass = 0; pass < 2; ++pass) {
    const int tau = pass * 1024 + tid;
    const int row = tau >> 5;         // 0..63
    const int sub = tau & 31;
    const int s   = sub >> 2;
    const int ak  = sub & 3;
    const int m = m0 + row;
    const size_t in_row = (mode == 0)
        ? ((size_t)(m & 7) * SEQ + (m >> 3))
        : (size_t)m;
    const float* xp = &X[in_row * ND + s * 32 + ak * 8];
    const float4 x0 = *(const float4*)(xp);
    const float4 x1 = *(const float4*)(xp + 4);
    const float a[8] = {x0.x, x0.y, x0.z, x0.w, x1.x, x1.y, x1.z, x1.w};
    f16x8 vh, vl;
    #pragma unroll
    for (int j = 0; j < 8; ++j) {
      const fp16_t h = (fp16_t)a[j];
      vh[j] = h;
      vl[j] = (fp16_t)((a[j] - (float)h) * LOSC);
    }
    const int off = (((row >> 4) * 8 + s) << 10) +
                    (((ak << 4) | (row & 15)) ^ s) * 16;
    *(f16x8*)(Xhb + off) = vh;
    *(f16x8*)(Xlb + off) = vl;
  }

  // resident M^T frags (A-operand), PINNED in VGPRs
  f16x8 MH[8], ML[8];
  #pragma unroll
  for (int s = 0; s < 8; ++s) {
    const size_t fo = (((size_t)w * 8 + s) * 64 + lane) * 8;
    MH[s] = *(const f16x8*)&Mhi[fo];
    ML[s] = *(const f16x8*)&Mlo[fo];
    pin(MH[s]);
    pin(ML[s]);
  }
  __syncthreads();

  f32x4 accm[4], accl[4];
  #pragma unroll
  for (int mt = 0; mt < 4; ++mt) {
    accm[mt] = (f32x4)0.0f;
    accl[mt] = (f32x4)0.0f;
  }

  #pragma unroll
  for (int s = 0; s < 8; ++s) {
    #pragma unroll
    for (int mt = 0; mt < 4; ++mt) {
      const int byte = ((mt * 8 + s) << 10) + ((((akg << 4) | br) ^ s) << 4);
      const f16x8 bh = *(const f16x8*)(Xhb + byte);
      const f16x8 bl = *(const f16x8*)(Xlb + byte);
      accm[mt] = __builtin_amdgcn_mfma_f32_16x16x32_f16(MH[s], bh, accm[mt], 0, 0, 0);
      accl[mt] = __builtin_amdgcn_mfma_f32_16x16x32_f16(ML[s], bh, accl[mt], 0, 0, 0);
      accl[mt] = __builtin_amdgcn_mfma_f32_16x16x32_f16(MH[s], bl, accl[mt], 0, 0, 0);
    }
  }

  #pragma unroll
  for (int mt = 0; mt < 4; ++mt) {
    const int m = m0 + mt * 16 + br;            // output row (X-row)
    const size_t out_row = (mode == 1)
        ? ((size_t)(m & 7) * SEQ + (m >> 3))
        : (size_t)m;
    float4 o;
    o.x = accm[mt][0] + accl[mt][0] * LOINV;
    o.y = accm[mt][1] + accl[mt][1] * LOINV;
    o.z = accm[mt][2] + accl[mt][2] * LOINV;
    o.w = accm[mt][3] + accl[mt][3] * LOINV;
    *(float4*)&Out[out_row * ND + w * 16 + akg * 4] = o;
  }
}

// ---------- unified MFMA recurrence kernel (swapped operands) ----------
// Each block runs TWO independent 8-row sequences (seq = blockIdx.x*2 + rowgrp).
// For nupd steps: h = h @ Mult + In[(seq*gstride + j)*NB + b].
// Init: null -> zero; init_bcast -> Init[col]; else Init[(seq*NB+b)*ND+col].
// entry_mode=0: OutEach written at (seq*gstride + j).
// entry_mode=1: OutEach gets Init at (seq*gstride), step-j state at (.. + j + 1).
// OutFinal: final state at row (seq*NB+b).
__global__ __launch_bounds__(1024, 2) void mfma_rscan(
    const fp16_t* __restrict__ Mh, const fp16_t* __restrict__ Ml,
    const float* __restrict__ Init,
    const float* In,
    float* OutEach,
    float* __restrict__ OutFinal,
    int nupd, int gstride, int nseq, int init_bcast, int entry_mode) {
  const int seq0 = blockIdx.x * 2;
  const int tid  = threadIdx.x;
  const int lane = tid & 63;
  const int w    = tid >> 6;          // 16 waves, state-col tile w
  const int br   = lane & 15;         // batch row 0..15
  const int akg  = lane >> 4;

  __shared__ fp16_t hH[2][8 * 512];   // [buf][slice-linear 8KB]
  __shared__ fp16_t hL[2][8 * 512];

  // init h (buf 0), slice-linear
  {
    const int task = tid >> 1;        // 0..511
    const int half = tid & 1;
    const int row  = task & 15;
    const int s    = (task >> 4) & 7;
    const int ak   = task >> 7;       // 0..3
    const int sq = seq0 + (row >> 3);
    const int b  = row & 7;
    const int c0 = s * 32 + ak * 8 + half * 4;
    f32x4 v = (f32x4)0.0f;
    if (Init != nullptr && sq < nseq) {
      const size_t off = init_bcast ? (size_t)c0
                                    : ((size_t)sq * NBATCH + b) * ND + c0;
      v = *(const f32x4*)&Init[off];
      if (entry_mode && OutEach != nullptr)
        *(f32x4*)&OutEach[((size_t)sq * gstride * NBATCH + b) * ND + c0] = v;
    }
    f16x4 vh, vl;
    #pragma unroll
    for (int j = 0; j < 4; ++j) {
      const fp16_t h = (fp16_t)v[j];
      vh[j] = h;
      vl[j] = (fp16_t)((v[j] - (float)h) * LOSC);
    }
    const int off = (s << 10) + ((((ak << 4) | row) ^ s) << 4) + half * 8;
    *(f16x4*)((char*)hH[0] + off) = vh;
    *(f16x4*)((char*)hL[0] + off) = vl;
  }

  // resident A^T frags (A-operand), PINNED in VGPRs
  f16x8 AH[8], AL[8];
  #pragma unroll
  for (int s = 0; s < 8; ++s) {
    const size_t fo = (((size_t)w * 8 + s) * 64 + lane) * 8;
    AH[s] = *(const f16x8*)&Mh[fo];
    AL[s] = *(const f16x8*)&Ml[fo];
    pin(AH[s]);
    pin(AL[s]);
  }
  __syncthreads();

  // this lane's output: batch-row br -> (seq, b); 4 consecutive state cols
  const int sq   = seq0 + (br >> 3);
  const int b    = br & 7;
  const bool live = (sq < nseq);
  const int sqc  = live ? sq : (nseq - 1);     // clamp for safe loads
  const int col0 = w * 16 + akg * 4;

  // precomputed LDS offsets
  int rdoff[8];
  #pragma unroll
  for (int s = 0; s < 8; ++s)
    rdoff[s] = (s << 10) + ((((akg << 4) | br) ^ s) << 4);
  const int sw   = col0 >> 5;
  const int akr  = (col0 >> 3) & 3;
  const int wroff = (sw << 10) + ((((akr << 4) | br) ^ sw) << 4) + (col0 & 7) * 2;

  f32x4 uv = *(const f32x4*)&In[((size_t)(sqc * gstride) * NBATCH + b) * ND + col0];
  f32x4 uvn;
  f32x4 res;
  int p = 0;
  for (int j = 0; j < nupd; ++j) {
    if (j + 1 < nupd)
      uvn = *(const f32x4*)&In[((size_t)(sqc * gstride + j + 1) * NBATCH + b) * ND + col0];
    const char* rH = (const char*)hH[p];
    const char* rL = (const char*)hL[p];
    f32x4 accm = uv, acclA = (f32x4)0.0f, acclB = (f32x4)0.0f;
    #pragma unroll
    for (int s = 0; s < 8; ++s) {
      const f16x8 bh = *(const f16x8*)(rH + rdoff[s]);
      const f16x8 bl = *(const f16x8*)(rL + rdoff[s]);
      accm  = __builtin_amdgcn_mfma_f32_16x16x32_f16(AH[s], bh, accm,  0, 0, 0);
      acclA = __builtin_amdgcn_mfma_f32_16x16x32_f16(AL[s], bh, acclA, 0, 0, 0);
      acclB = __builtin_amdgcn_mfma_f32_16x16x32_f16(AH[s], bl, acclB, 0, 0, 0);
    }
    #pragma unroll
    for (int r = 0; r < 4; ++r) res[r] = accm[r] + (acclA[r] + acclB[r]) * LOINV;
    // write new h into the OTHER buffer (no barrier needed before writes)
    {
      f16x4 vh, vl;
      #pragma unroll
      for (int r = 0; r < 4; ++r) {
        const fp16_t hh = (fp16_t)res[r];
        vh[r] = hh;
        vl[r] = (fp16_t)((res[r] - (float)hh) * LOSC);
      }
      *(f16x4*)((char*)hH[p ^ 1] + wroff) = vh;
      *(f16x4*)((char*)hL[p ^ 1] + wroff) = vl;
    }
    if (OutEach != nullptr && live) {
      const size_t pos = entry_mode ? (size_t)(sq * gstride + j + 1)
                                    : (size_t)(sq * gstride + j);
      *(f32x4*)&OutEach[(pos * NBATCH + b) * ND + col0] = res;
    }
    uv = uvn;
    p ^= 1;
    __syncthreads();                  // new h visible; old buf free for reuse
  }

  if (OutFinal != nullptr && live)
    *(f32x4*)&OutFinal[((size_t)sq * NBATCH + b) * ND + col0] = res;
}

// ---------- dense 256x256 f32 GEMM (A-power chain) ----------
__global__ __launch_bounds__(256) void gemm256(const float* __restrict__ X,
                                               const float* __restrict__ Y,
                                               float* __restrict__ Out) {
  const int m0 = blockIdx.x * 4;
  const int n  = threadIdx.x;
  __shared__ float Xs[ND][4];
  #pragma unroll
  for (int r = 0; r < 4; ++r) Xs[n][r] = X[(m0 + r) * ND + n];
  __syncthreads();
  float a0 = 0.f, a1 = 0.f, a2 = 0.f, a3 = 0.f;
  #pragma unroll 8
  for (int k = 0; k < ND; ++k) {
    const float yv = Y[k * ND + n];
    const float4 xv = *(const float4*)&Xs[k][0];
    a0 = fmaf(xv.x, yv, a0);
    a1 = fmaf(xv.y, yv, a1);
    a2 = fmaf(xv.z, yv, a2);
    a3 = fmaf(xv.w, yv, a3);
  }
  Out[(m0 + 0) * ND + n] = a0;
  Out[(m0 + 1) * ND + n] = a1;
  Out[(m0 + 2) * ND + n] = a2;
  Out[(m0 + 3) * ND + n] = a3;
}

extern "C" void kernel_launch(void* const* d_in, const int* in_sizes, int n_in,
                              void* d_out, int out_size, void* d_ws, size_t ws_size,
                              hipStream_t stream) {
  const float* x  = (const float*)d_in[0];
  const float* A  = (const float*)d_in[1];
  const float* Bm = (const float*)d_in[2];
  const float* Cm = (const float*)d_in[3];
  const float* h0 = (const float*)d_in[4];
  float* y = (float*)d_out;

  float* U    = (float*)d_ws;                        // 8,388,608
  float* t0   = U + (size_t)SEQ * NBATCH * ND;       // 65,536 (reused for A8 frags)
  float* t1   = t0 + ND * ND;                        // 65,536 (reused for A128 frags)
  float* A8   = t1 + ND * ND;
  float* A128 = A8 + ND * ND;
  float* E    = A128 + ND * ND;                      // 1,048,576
  float* Sg   = E + (size_t)NCHUNK * NBATCH * ND;    // 65,536
  float* G    = Sg + (size_t)NGRP * NBATCH * ND;     // 65,536
  float* Hc   = G + (size_t)NGRP * NBATCH * ND;      // 1,048,576
  fp16_t* fA_hi = (fp16_t*)(Hc + (size_t)NCHUNK * NBATCH * ND);
  fp16_t* fA_lo = fA_hi + ND * ND;
  fp16_t* fB_hi = fA_lo + ND * ND;
  fp16_t* fB_lo = fB_hi + ND * ND;
  fp16_t* fC_hi = fB_lo + ND * ND;
  fp16_t* fC_lo = fC_hi + ND * ND;
  fp16_t* fA8_hi   = (fp16_t*)t0;
  fp16_t* fA8_lo   = fA8_hi + ND * ND;
  fp16_t* fA128_hi = (fp16_t*)t1;
  fp16_t* fA128_lo = fA128_hi + ND * ND;

  // pack A,B,C into fragment arrays
  prep_frags3<<<384, 64, 0, stream>>>(A, Bm, Cm, fA_hi, fA_lo, fB_hi, fB_lo,
                                      fC_hi, fC_lo);

  // A powers (f32): A^8, A^128  (t0/t1 scratch, then freed)
  gemm256<<<64, 256, 0, stream>>>(A,  A,  t0);       // A^2
  gemm256<<<64, 256, 0, stream>>>(t0, t0, t1);       // A^4
  gemm256<<<64, 256, 0, stream>>>(t1, t1, A8);       // A^8
  gemm256<<<64, 256, 0, stream>>>(A8, A8, t0);       // A^16
  gemm256<<<64, 256, 0, stream>>>(t0, t0, t1);       // A^32
  gemm256<<<64, 256, 0, stream>>>(t1, t1, t0);       // A^64
  gemm256<<<64, 256, 0, stream>>>(t0, t0, A128);     // A^128

  // pack A8/A128 into frags (t0/t1 storage reuse)
  prep_frags2<<<256, 64, 0, stream>>>(A8, A128, fA8_hi, fA8_lo,
                                      fA128_hi, fA128_lo);

  // U = x @ B
  mfma_gemm<<<512, 1024, 0, stream>>>(x, fB_hi, fB_lo, U, 0);

  // chunk local ends: E[c] = scan(0; u over chunk c)
  mfma_rscan<<<NCHUNK / 2, 1024, 0, stream>>>(fA_hi, fA_lo, nullptr, U,
                                              nullptr, E, CHUNK, CHUNK,
                                              NCHUNK, 0, 0);

  // group collect: Sg[g] = scan(0; E over group g) with A^8
  mfma_rscan<<<NGRP / 2, 1024, 0, stream>>>(fA8_hi, fA8_lo, nullptr, E,
                                            nullptr, Sg, GSZ, GSZ, NGRP, 0, 0);

  // top scan: G[0]=h0; G[g+1] = G[g]@A128 + Sg[g]
  mfma_rscan<<<1, 1024, 0, stream>>>(fA128_hi, fA128_lo, h0, Sg,
                                     G, nullptr, NGRP - 1, NGRP, 1, 1, 1);

  // group entries: Hc[g*GSZ]=G[g]; Hc[c+1] = Hc[c]@A8 + E[c]
  mfma_rscan<<<NGRP / 2, 1024, 0, stream>>>(fA8_hi, fA8_lo, G, E,
                                            Hc, nullptr, GSZ - 1, GSZ, NGRP,
                                            0, 1);

  // final chunk scan from true entries; h overwrites U
  mfma_rscan<<<NCHUNK / 2, 1024, 0, stream>>>(fA_hi, fA_lo, Hc, U,
                                              U, nullptr, CHUNK, CHUNK,
                                              NCHUNK, 0, 0);

  // y = h @ C
  mfma_gemm<<<512, 1024, 0, stream>>>(U, fC_hi, fC_lo, y, 1);
}

// Round 12
// 266.449 us; speedup vs baseline: 1.3228x; 1.0114x over previous
//
#include <hip/hip_runtime.h>

// Linear RNN scan: h_t = h_{t-1}@A + x_t@B ; y_t = h_t@C
// B=8, S=4096, IN=STATE=OUT=256.
// MFMA 16x16x32 f16, 2-term split (hi + 2048*lo), f32 accumulate.
// Swapped operands: out^T = M^T @ in^T (frags = A-operand, LDS tile = B-operand).
// Slice-linear LDS: per slice s a 1024B region, slot ((ak<<4)|row)^s -> conflict-free.
// UNFUSED round-7 structure + frag pin + *** LDS OCCUPANCY SHAPING ***:
//   dead ~56KB shared pad forces 1 block/CU -> backend VGPR budget 64 -> 128
//   -> the 64-VGPR resident frag set actually stays in registers.

#define SEQ    4096
#define NBATCH 8
#define ND     256
#define CHUNK  8
#define NCHUNK 512
#define GSZ    16
#define NGRP   32
#define LOSC   2048.0f
#define LOINV  (1.0f/2048.0f)

typedef _Float16 fp16_t;
typedef __attribute__((ext_vector_type(8))) _Float16 f16x8;
typedef __attribute__((ext_vector_type(4))) _Float16 f16x4;
typedef __attribute__((ext_vector_type(4))) float f32x4;

// Force a loaded fragment to stay materialized in VGPRs.
__device__ __forceinline__ void pin(f16x8& x) { asm volatile("" : "+v"(x)); }

// ---------- pack A,B,C into frag arrays (hi/lo f16) ----------
// frag linear index: ((tile*8 + slice)*64 + lane)*8 + j
// value = M[k][n], k = slice*32 + (lane>>4)*8 + j, n = tile*16 + (lane&15)
__global__ __launch_bounds__(64) void prep_frags3(
    const float* __restrict__ A, const float* __restrict__ B,
    const float* __restrict__ C,
    fp16_t* __restrict__ fAh, fp16_t* __restrict__ fAl,
    fp16_t* __restrict__ fBh, fp16_t* __restrict__ fBl,
    fp16_t* __restrict__ fCh, fp16_t* __restrict__ fCl) {
  const int which = blockIdx.x >> 7;
  const int blk   = blockIdx.x & 127;
  const float* M = (which == 0) ? A : (which == 1) ? B : C;
  fp16_t* hi = (which == 0) ? fAh : (which == 1) ? fBh : fCh;
  fp16_t* lo = (which == 0) ? fAl : (which == 1) ? fBl : fCl;
  const int lane = threadIdx.x;
  const int tile = blk >> 3, slice = blk & 7;
  const int n  = tile * 16 + (lane & 15);
  const int k0 = slice * 32 + (lane >> 4) * 8;
  f16x8 vh, vl;
  #pragma unroll
  for (int j = 0; j < 8; ++j) {
    const float v = M[(size_t)(k0 + j) * ND + n];
    const fp16_t h = (fp16_t)v;
    vh[j] = h;
    vl[j] = (fp16_t)((v - (float)h) * LOSC);
  }
  const size_t fo = ((size_t)blk * 64 + lane) * 8;
  *(f16x8*)&hi[fo] = vh;
  *(f16x8*)&lo[fo] = vl;
}

// ---------- pack A8, A128 into frag arrays ----------
__global__ __launch_bounds__(64) void prep_frags2(
    const float* __restrict__ M0, const float* __restrict__ M1,
    fp16_t* __restrict__ h0p, fp16_t* __restrict__ l0p,
    fp16_t* __restrict__ h1p, fp16_t* __restrict__ l1p) {
  const int which = blockIdx.x >> 7;
  const int blk   = blockIdx.x & 127;
  const float* M = (which == 0) ? M0 : M1;
  fp16_t* hi = (which == 0) ? h0p : h1p;
  fp16_t* lo = (which == 0) ? l0p : l1p;
  const int lane = threadIdx.x;
  const int tile = blk >> 3, slice = blk & 7;
  const int n  = tile * 16 + (lane & 15);
  const int k0 = slice * 32 + (lane >> 4) * 8;
  f16x8 vh, vl;
  #pragma unroll
  for (int j = 0; j < 8; ++j) {
    const float v = M[(size_t)(k0 + j) * ND + n];
    const fp16_t h = (fp16_t)v;
    vh[j] = h;
    vl[j] = (fp16_t)((v - (float)h) * LOSC);
  }
  const size_t fo = ((size_t)blk * 64 + lane) * 8;
  *(f16x8*)&hi[fo] = vh;
  *(f16x8*)&lo[fo] = vl;
}

// ---------- MFMA GEMM: Out[m][:] = X[m][:] @ M,  m = s*8+b, M-block = 64 ----------
// mode 0 (xb): X rows remapped from x[b][s][:];  mode 1 (y): Out remapped to y[b][s][:]
__global__ __launch_bounds__(1024, 4) void mfma_gemm(const float* __restrict__ X,
                                                     const fp16_t* __restrict__ Mhi,
                                                     const fp16_t* __restrict__ Mlo,
                                                     float* __restrict__ Out,
                                                     int mode) {
  const int m0   = blockIdx.x * 64;
  const int tid  = threadIdx.x;
  const int lane = tid & 63;
  const int w    = tid >> 6;          // 16 waves, M-col tile w
  const int br   = lane & 15;
  const int akg  = lane >> 4;

  __shared__ fp16_t Xh[32 * 512];     // 32 regions x 1024B (slice-linear) = 32KB
  __shared__ fp16_t Xl[32 * 512];     // 32KB
  __shared__ char   occ_pad[24 * 1024]; // 64+24=88KB -> 1 block/CU -> VGPR budget 128
  if (mode == -12345) ((volatile char*)occ_pad)[tid] = 1;  // never true; keeps pad
  char* Xhb = (char*)Xh;
  char* Xlb = (char*)Xl;

  // stage 64 rows of X -> hi/lo, slice-linear layout (fully coalesced global)
  #pragma unroll
  for (int pass = 0; pass < 2; ++pass) {
    const int tau = pass * 1024 + tid;
    const int row = tau >> 5;         // 0..63
    const int sub = tau & 31;
    const int s   = sub >> 2;
    const int ak  = sub & 3;
    const int m = m0 + row;
    const size_t in_row = (mode == 0)
        ? ((size_t)(m & 7) * SEQ + (m >> 3))
        : (size_t)m;
    const float* xp = &X[in_row * ND + s * 32 + ak * 8];
    const float4 x0 = *(const float4*)(xp);
    const float4 x1 = *(const float4*)(xp + 4);
    const float a[8] = {x0.x, x0.y, x0.z, x0.w, x1.x, x1.y, x1.z, x1.w};
    f16x8 vh, vl;
    #pragma unroll
    for (int j = 0; j < 8; ++j) {
      const fp16_t h = (fp16_t)a[j];
      vh[j] = h;
      vl[j] = (fp16_t)((a[j] - (float)h) * LOSC);
    }
    const int off = (((row >> 4) * 8 + s) << 10) +
                    (((ak << 4) | (row & 15)) ^ s) * 16;
    *(f16x8*)(Xhb + off) = vh;
    *(f16x8*)(Xlb + off) = vl;
  }

  // resident M^T frags (A-operand), PINNED in VGPRs
  f16x8 MH[8], ML[8];
  #pragma unroll
  for (int s = 0; s < 8; ++s) {
    const size_t fo = (((size_t)w * 8 + s) * 64 + lane) * 8;
    MH[s] = *(const f16x8*)&Mhi[fo];
    ML[s] = *(const f16x8*)&Mlo[fo];
    pin(MH[s]);
    pin(ML[s]);
  }
  __syncthreads();

  f32x4 accm[4], accl[4];
  #pragma unroll
  for (int mt = 0; mt < 4; ++mt) {
    accm[mt] = (f32x4)0.0f;
    accl[mt] = (f32x4)0.0f;
  }

  #pragma unroll
  for (int s = 0; s < 8; ++s) {
    #pragma unroll
    for (int mt = 0; mt < 4; ++mt) {
      const int byte = ((mt * 8 + s) << 10) + ((((akg << 4) | br) ^ s) << 4);
      const f16x8 bh = *(const f16x8*)(Xhb + byte);
      const f16x8 bl = *(const f16x8*)(Xlb + byte);
      accm[mt] = __builtin_amdgcn_mfma_f32_16x16x32_f16(MH[s], bh, accm[mt], 0, 0, 0);
      accl[mt] = __builtin_amdgcn_mfma_f32_16x16x32_f16(ML[s], bh, accl[mt], 0, 0, 0);
      accl[mt] = __builtin_amdgcn_mfma_f32_16x16x32_f16(MH[s], bl, accl[mt], 0, 0, 0);
    }
  }

  #pragma unroll
  for (int mt = 0; mt < 4; ++mt) {
    const int m = m0 + mt * 16 + br;            // output row (X-row)
    const size_t out_row = (mode == 1)
        ? ((size_t)(m & 7) * SEQ + (m >> 3))
        : (size_t)m;
    float4 o;
    o.x = accm[mt][0] + accl[mt][0] * LOINV;
    o.y = accm[mt][1] + accl[mt][1] * LOINV;
    o.z = accm[mt][2] + accl[mt][2] * LOINV;
    o.w = accm[mt][3] + accl[mt][3] * LOINV;
    *(float4*)&Out[out_row * ND + w * 16 + akg * 4] = o;
  }
}

// ---------- unified MFMA recurrence kernel (swapped operands) ----------
// Each block runs TWO independent 8-row sequences (seq = blockIdx.x*2 + rowgrp).
// For nupd steps: h = h @ Mult + In[(seq*gstride + j)*NB + b].
// Init: null -> zero; init_bcast -> Init[col]; else Init[(seq*NB+b)*ND+col].
// entry_mode=0: OutEach written at (seq*gstride + j).
// entry_mode=1: OutEach gets Init at (seq*gstride), step-j state at (.. + j + 1).
// OutFinal: final state at row (seq*NB+b).
__global__ __launch_bounds__(1024, 4) void mfma_rscan(
    const fp16_t* __restrict__ Mh, const fp16_t* __restrict__ Ml,
    const float* __restrict__ Init,
    const float* In,
    float* OutEach,
    float* __restrict__ OutFinal,
    int nupd, int gstride, int nseq, int init_bcast, int entry_mode) {
  const int seq0 = blockIdx.x * 2;
  const int tid  = threadIdx.x;
  const int lane = tid & 63;
  const int w    = tid >> 6;          // 16 waves, state-col tile w
  const int br   = lane & 15;         // batch row 0..15
  const int akg  = lane >> 4;

  __shared__ fp16_t hH[2][8 * 512];   // [buf][slice-linear 8KB] = 16KB
  __shared__ fp16_t hL[2][8 * 512];   // 16KB
  __shared__ char   occ_pad[56 * 1024]; // 32+56=88KB -> 1 block/CU -> VGPR budget 128
  if (nupd == -12345) ((volatile char*)occ_pad)[tid] = 1;  // never true; keeps pad

  // init h (buf 0), slice-linear
  {
    const int task = tid >> 1;        // 0..511
    const int half = tid & 1;
    const int row  = task & 15;
    const int s    = (task >> 4) & 7;
    const int ak   = task >> 7;       // 0..3
    const int sq = seq0 + (row >> 3);
    const int b  = row & 7;
    const int c0 = s * 32 + ak * 8 + half * 4;
    f32x4 v = (f32x4)0.0f;
    if (Init != nullptr && sq < nseq) {
      const size_t off = init_bcast ? (size_t)c0
                                    : ((size_t)sq * NBATCH + b) * ND + c0;
      v = *(const f32x4*)&Init[off];
      if (entry_mode && OutEach != nullptr)
        *(f32x4*)&OutEach[((size_t)sq * gstride * NBATCH + b) * ND + c0] = v;
    }
    f16x4 vh, vl;
    #pragma unroll
    for (int j = 0; j < 4; ++j) {
      const fp16_t h = (fp16_t)v[j];
      vh[j] = h;
      vl[j] = (fp16_t)((v[j] - (float)h) * LOSC);
    }
    const int off = (s << 10) + ((((ak << 4) | row) ^ s) << 4) + half * 8;
    *(f16x4*)((char*)hH[0] + off) = vh;
    *(f16x4*)((char*)hL[0] + off) = vl;
  }

  // resident A^T frags (A-operand), PINNED in VGPRs
  f16x8 AH[8], AL[8];
  #pragma unroll
  for (int s = 0; s < 8; ++s) {
    const size_t fo = (((size_t)w * 8 + s) * 64 + lane) * 8;
    AH[s] = *(const f16x8*)&Mh[fo];
    AL[s] = *(const f16x8*)&Ml[fo];
    pin(AH[s]);
    pin(AL[s]);
  }
  __syncthreads();

  // this lane's output: batch-row br -> (seq, b); 4 consecutive state cols
  const int sq   = seq0 + (br >> 3);
  const int b    = br & 7;
  const bool live = (sq < nseq);
  const int sqc  = live ? sq : (nseq - 1);     // clamp for safe loads
  const int col0 = w * 16 + akg * 4;

  // precomputed LDS offsets
  int rdoff[8];
  #pragma unroll
  for (int s = 0; s < 8; ++s)
    rdoff[s] = (s << 10) + ((((akg << 4) | br) ^ s) << 4);
  const int sw   = col0 >> 5;
  const int akr  = (col0 >> 3) & 3;
  const int wroff = (sw << 10) + ((((akr << 4) | br) ^ sw) << 4) + (col0 & 7) * 2;

  f32x4 uv = *(const f32x4*)&In[((size_t)(sqc * gstride) * NBATCH + b) * ND + col0];
  f32x4 uvn;
  f32x4 res;
  int p = 0;
  for (int j = 0; j < nupd; ++j) {
    if (j + 1 < nupd)
      uvn = *(const f32x4*)&In[((size_t)(sqc * gstride + j + 1) * NBATCH + b) * ND + col0];
    const char* rH = (const char*)hH[p];
    const char* rL = (const char*)hL[p];
    f32x4 accm = uv, acclA = (f32x4)0.0f, acclB = (f32x4)0.0f;
    #pragma unroll
    for (int s = 0; s < 8; ++s) {
      const f16x8 bh = *(const f16x8*)(rH + rdoff[s]);
      const f16x8 bl = *(const f16x8*)(rL + rdoff[s]);
      accm  = __builtin_amdgcn_mfma_f32_16x16x32_f16(AH[s], bh, accm,  0, 0, 0);
      acclA = __builtin_amdgcn_mfma_f32_16x16x32_f16(AL[s], bh, acclA, 0, 0, 0);
      acclB = __builtin_amdgcn_mfma_f32_16x16x32_f16(AH[s], bl, acclB, 0, 0, 0);
    }
    #pragma unroll
    for (int r = 0; r < 4; ++r) res[r] = accm[r] + (acclA[r] + acclB[r]) * LOINV;
    // write new h into the OTHER buffer (no barrier needed before writes)
    {
      f16x4 vh, vl;
      #pragma unroll
      for (int r = 0; r < 4; ++r) {
        const fp16_t hh = (fp16_t)res[r];
        vh[r] = hh;
        vl[r] = (fp16_t)((res[r] - (float)hh) * LOSC);
      }
      *(f16x4*)((char*)hH[p ^ 1] + wroff) = vh;
      *(f16x4*)((char*)hL[p ^ 1] + wroff) = vl;
    }
    if (OutEach != nullptr && live) {
      const size_t pos = entry_mode ? (size_t)(sq * gstride + j + 1)
                                    : (size_t)(sq * gstride + j);
      *(f32x4*)&OutEach[(pos * NBATCH + b) * ND + col0] = res;
    }
    uv = uvn;
    p ^= 1;
    __syncthreads();                  // new h visible; old buf free for reuse
  }

  if (OutFinal != nullptr && live)
    *(f32x4*)&OutFinal[((size_t)sq * NBATCH + b) * ND + col0] = res;
}

// ---------- dense 256x256 f32 GEMM (A-power chain) ----------
__global__ __launch_bounds__(256) void gemm256(const float* __restrict__ X,
                                               const float* __restrict__ Y,
                                               float* __restrict__ Out) {
  const int m0 = blockIdx.x * 4;
  const int n  = threadIdx.x;
  __shared__ float Xs[ND][4];
  #pragma unroll
  for (int r = 0; r < 4; ++r) Xs[n][r] = X[(m0 + r) * ND + n];
  __syncthreads();
  float a0 = 0.f, a1 = 0.f, a2 = 0.f, a3 = 0.f;
  #pragma unroll 8
  for (int k = 0; k < ND; ++k) {
    const float yv = Y[k * ND + n];
    const float4 xv = *(const float4*)&Xs[k][0];
    a0 = fmaf(xv.x, yv, a0);
    a1 = fmaf(xv.y, yv, a1);
    a2 = fmaf(xv.z, yv, a2);
    a3 = fmaf(xv.w, yv, a3);
  }
  Out[(m0 + 0) * ND + n] = a0;
  Out[(m0 + 1) * ND + n] = a1;
  Out[(m0 + 2) * ND + n] = a2;
  Out[(m0 + 3) * ND + n] = a3;
}

extern "C" void kernel_launch(void* const* d_in, const int* in_sizes, int n_in,
                              void* d_out, int out_size, void* d_ws, size_t ws_size,
                              hipStream_t stream) {
  const float* x  = (const float*)d_in[0];
  const float* A  = (const float*)d_in[1];
  const float* Bm = (const float*)d_in[2];
  const float* Cm = (const float*)d_in[3];
  const float* h0 = (const float*)d_in[4];
  float* y = (float*)d_out;

  float* U    = (float*)d_ws;                        // 8,388,608
  float* t0   = U + (size_t)SEQ * NBATCH * ND;       // 65,536 (reused for A8 frags)
  float* t1   = t0 + ND * ND;                        // 65,536 (reused for A128 frags)
  float* A8   = t1 + ND * ND;
  float* A128 = A8 + ND * ND;
  float* E    = A128 + ND * ND;                      // 1,048,576
  float* Sg   = E + (size_t)NCHUNK * NBATCH * ND;    // 65,536
  float* G    = Sg + (size_t)NGRP * NBATCH * ND;     // 65,536
  float* Hc   = G + (size_t)NGRP * NBATCH * ND;      // 1,048,576
  fp16_t* fA_hi = (fp16_t*)(Hc + (size_t)NCHUNK * NBATCH * ND);
  fp16_t* fA_lo = fA_hi + ND * ND;
  fp16_t* fB_hi = fA_lo + ND * ND;
  fp16_t* fB_lo = fB_hi + ND * ND;
  fp16_t* fC_hi = fB_lo + ND * ND;
  fp16_t* fC_lo = fC_hi + ND * ND;
  fp16_t* fA8_hi   = (fp16_t*)t0;
  fp16_t* fA8_lo   = fA8_hi + ND * ND;
  fp16_t* fA128_hi = (fp16_t*)t1;
  fp16_t* fA128_lo = fA128_hi + ND * ND;

  // pack A,B,C into fragment arrays
  prep_frags3<<<384, 64, 0, stream>>>(A, Bm, Cm, fA_hi, fA_lo, fB_hi, fB_lo,
                                      fC_hi, fC_lo);

  // A powers (f32): A^8, A^128  (t0/t1 scratch, then freed)
  gemm256<<<64, 256, 0, stream>>>(A,  A,  t0);       // A^2
  gemm256<<<64, 256, 0, stream>>>(t0, t0, t1);       // A^4
  gemm256<<<64, 256, 0, stream>>>(t1, t1, A8);       // A^8
  gemm256<<<64, 256, 0, stream>>>(A8, A8, t0);       // A^16
  gemm256<<<64, 256, 0, stream>>>(t0, t0, t1);       // A^32
  gemm256<<<64, 256, 0, stream>>>(t1, t1, t0);       // A^64
  gemm256<<<64, 256, 0, stream>>>(t0, t0, A128);     // A^128

  // pack A8/A128 into frags (t0/t1 storage reuse)
  prep_frags2<<<256, 64, 0, stream>>>(A8, A128, fA8_hi, fA8_lo,
                                      fA128_hi, fA128_lo);

  // U = x @ B
  mfma_gemm<<<512, 1024, 0, stream>>>(x, fB_hi, fB_lo, U, 0);

  // chunk local ends: E[c] = scan(0; u over chunk c)
  mfma_rscan<<<NCHUNK / 2, 1024, 0, stream>>>(fA_hi, fA_lo, nullptr, U,
                                              nullptr, E, CHUNK, CHUNK,
                                              NCHUNK, 0, 0);

  // group collect: Sg[g] = scan(0; E over group g) with A^8
  mfma_rscan<<<NGRP / 2, 1024, 0, stream>>>(fA8_hi, fA8_lo, nullptr, E,
                                            nullptr, Sg, GSZ, GSZ, NGRP, 0, 0);

  // top scan: G[0]=h0; G[g+1] = G[g]@A128 + Sg[g]
  mfma_rscan<<<1, 1024, 0, stream>>>(fA128_hi, fA128_lo, h0, Sg,
                                     G, nullptr, NGRP - 1, NGRP, 1, 1, 1);

  // group entries: Hc[g*GSZ]=G[g]; Hc[c+1] = Hc[c]@A8 + E[c]
  mfma_rscan<<<NGRP / 2, 1024, 0, stream>>>(fA8_hi, fA8_lo, G, E,
                                            Hc, nullptr, GSZ - 1, GSZ, NGRP,
                                            0, 1);

  // final chunk scan from true entries; h overwrites U
  mfma_rscan<<<NCHUNK / 2, 1024, 0, stream>>>(fA_hi, fA_lo, Hc, U,
                                              U, nullptr, CHUNK, CHUNK,
                                              NCHUNK, 0, 0);

  // y = h @ C
  mfma_gemm<<<512, 1024, 0, stream>>>(U, fC_hi, fC_lo, y, 1);
}

// Round 13
// 237.641 us; speedup vs baseline: 1.4831x; 1.1212x over previous
//
#include <hip/hip_runtime.h>

// Linear RNN scan: h_t = h_{t-1}@A + x_t@B ; y_t = h_t@C
// B=8, S=4096, IN=STATE=OUT=256.
// MFMA 16x16x32 f16, 2-term split (hi + 2048*lo), f32 accumulate.
// Swapped operands: out^T = M^T @ in^T (frags = A-operand, LDS tile = B-operand).
// Slice-linear LDS: per slice s a 1024B region, slot ((ak<<4)|row)^s -> conflict-free.
// Round-7 kernel bodies (best codegen: frags L2-resident, no pin, no pad).
// NEW: 4-level radix-8 scan hierarchy (8 x 8 x 8 x 8):
//   chunk passes: 512 seqs x 8 steps (256 blocks)       mult A
//   L1 collect/apply: 64 seqs x 8/7 steps (32 blocks)   mult A^8
//   L2 collect/apply: 8 seqs x 8/7 steps (4 blocks)     mult A^64
//   top: 1 seq x 7 steps (1 block)                      mult A^512
// Sequential depth 53 steps (was 78), 1-block level 7 steps (was 31).

#define SEQ    4096
#define NBATCH 8
#define ND     256
#define CHUNK  8
#define NCHUNK 512
#define LOSC   2048.0f
#define LOINV  (1.0f/2048.0f)

typedef _Float16 fp16_t;
typedef __attribute__((ext_vector_type(8))) _Float16 f16x8;
typedef __attribute__((ext_vector_type(4))) _Float16 f16x4;
typedef __attribute__((ext_vector_type(4))) float f32x4;

// ---------- pack three 256x256 f32 matrices into frag arrays (hi/lo f16) ----------
// frag linear index: ((tile*8 + slice)*64 + lane)*8 + j
// value = M[k][n], k = slice*32 + (lane>>4)*8 + j, n = tile*16 + (lane&15)
__global__ __launch_bounds__(64) void prep_frags3(
    const float* __restrict__ A, const float* __restrict__ B,
    const float* __restrict__ C,
    fp16_t* __restrict__ fAh, fp16_t* __restrict__ fAl,
    fp16_t* __restrict__ fBh, fp16_t* __restrict__ fBl,
    fp16_t* __restrict__ fCh, fp16_t* __restrict__ fCl) {
  const int which = blockIdx.x >> 7;
  const int blk   = blockIdx.x & 127;
  const float* M = (which == 0) ? A : (which == 1) ? B : C;
  fp16_t* hi = (which == 0) ? fAh : (which == 1) ? fBh : fCh;
  fp16_t* lo = (which == 0) ? fAl : (which == 1) ? fBl : fCl;
  const int lane = threadIdx.x;
  const int tile = blk >> 3, slice = blk & 7;
  const int n  = tile * 16 + (lane & 15);
  const int k0 = slice * 32 + (lane >> 4) * 8;
  f16x8 vh, vl;
  #pragma unroll
  for (int j = 0; j < 8; ++j) {
    const float v = M[(size_t)(k0 + j) * ND + n];
    const fp16_t h = (fp16_t)v;
    vh[j] = h;
    vl[j] = (fp16_t)((v - (float)h) * LOSC);
  }
  const size_t fo = ((size_t)blk * 64 + lane) * 8;
  *(f16x8*)&hi[fo] = vh;
  *(f16x8*)&lo[fo] = vl;
}

// ---------- MFMA GEMM: Out[m][:] = X[m][:] @ M,  m = s*8+b, M-block = 64 ----------
// mode 0 (xb): X rows remapped from x[b][s][:];  mode 1 (y): Out remapped to y[b][s][:]
__global__ __launch_bounds__(1024, 2) void mfma_gemm(const float* __restrict__ X,
                                                     const fp16_t* __restrict__ Mhi,
                                                     const fp16_t* __restrict__ Mlo,
                                                     float* __restrict__ Out,
                                                     int mode) {
  const int m0   = blockIdx.x * 64;
  const int tid  = threadIdx.x;
  const int lane = tid & 63;
  const int w    = tid >> 6;          // 16 waves, M-col tile w
  const int br   = lane & 15;
  const int akg  = lane >> 4;

  __shared__ fp16_t Xh[32 * 512];     // 32 regions x 1024B (slice-linear)
  __shared__ fp16_t Xl[32 * 512];
  char* Xhb = (char*)Xh;
  char* Xlb = (char*)Xl;

  // stage 64 rows of X -> hi/lo, slice-linear layout (fully coalesced global)
  #pragma unroll
  for (int pass = 0; pass < 2; ++pass) {
    const int tau = pass * 1024 + tid;
    const int row = tau >> 5;         // 0..63
    const int sub = tau & 31;
    const int s   = sub >> 2;
    const int ak  = sub & 3;
    const int m = m0 + row;
    const size_t in_row = (mode == 0)
        ? ((size_t)(m & 7) * SEQ + (m >> 3))
        : (size_t)m;
    const float* xp = &X[in_row * ND + s * 32 + ak * 8];
    const float4 x0 = *(const float4*)(xp);
    const float4 x1 = *(const float4*)(xp + 4);
    const float a[8] = {x0.x, x0.y, x0.z, x0.w, x1.x, x1.y, x1.z, x1.w};
    f16x8 vh, vl;
    #pragma unroll
    for (int j = 0; j < 8; ++j) {
      const fp16_t h = (fp16_t)a[j];
      vh[j] = h;
      vl[j] = (fp16_t)((a[j] - (float)h) * LOSC);
    }
    const int off = (((row >> 4) * 8 + s) << 10) +
                    (((ak << 4) | (row & 15)) ^ s) * 16;
    *(f16x8*)(Xhb + off) = vh;
    *(f16x8*)(Xlb + off) = vl;
  }

  // resident M^T frags (A-operand) for this wave's M-col tile
  f16x8 MH[8], ML[8];
  #pragma unroll
  for (int s = 0; s < 8; ++s) {
    const size_t fo = (((size_t)w * 8 + s) * 64 + lane) * 8;
    MH[s] = *(const f16x8*)&Mhi[fo];
    ML[s] = *(const f16x8*)&Mlo[fo];
  }
  __syncthreads();

  f32x4 accm[4], accl[4];
  #pragma unroll
  for (int mt = 0; mt < 4; ++mt) {
    accm[mt] = (f32x4)0.0f;
    accl[mt] = (f32x4)0.0f;
  }

  #pragma unroll
  for (int s = 0; s < 8; ++s) {
    #pragma unroll
    for (int mt = 0; mt < 4; ++mt) {
      const int byte = ((mt * 8 + s) << 10) + ((((akg << 4) | br) ^ s) << 4);
      const f16x8 bh = *(const f16x8*)(Xhb + byte);
      const f16x8 bl = *(const f16x8*)(Xlb + byte);
      accm[mt] = __builtin_amdgcn_mfma_f32_16x16x32_f16(MH[s], bh, accm[mt], 0, 0, 0);
      accl[mt] = __builtin_amdgcn_mfma_f32_16x16x32_f16(ML[s], bh, accl[mt], 0, 0, 0);
      accl[mt] = __builtin_amdgcn_mfma_f32_16x16x32_f16(MH[s], bl, accl[mt], 0, 0, 0);
    }
  }

  #pragma unroll
  for (int mt = 0; mt < 4; ++mt) {
    const int m = m0 + mt * 16 + br;            // output row (X-row)
    const size_t out_row = (mode == 1)
        ? ((size_t)(m & 7) * SEQ + (m >> 3))
        : (size_t)m;
    float4 o;
    o.x = accm[mt][0] + accl[mt][0] * LOINV;
    o.y = accm[mt][1] + accl[mt][1] * LOINV;
    o.z = accm[mt][2] + accl[mt][2] * LOINV;
    o.w = accm[mt][3] + accl[mt][3] * LOINV;
    *(float4*)&Out[out_row * ND + w * 16 + akg * 4] = o;
  }
}

// ---------- unified MFMA recurrence kernel (swapped operands) ----------
// Each block runs TWO independent 8-row sequences (seq = blockIdx.x*2 + rowgrp).
// For nupd steps: h = h @ Mult + In[(seq*gstride + j)*NB + b].
// Init: null -> zero; init_bcast -> Init[col]; else Init[(seq*NB+b)*ND+col].
// entry_mode=0: OutEach written at (seq*gstride + j).
// entry_mode=1: OutEach gets Init at (seq*gstride), step-j state at (.. + j + 1).
// OutFinal: final state at row (seq*NB+b).
__global__ __launch_bounds__(1024, 2) void mfma_rscan(
    const fp16_t* __restrict__ Mh, const fp16_t* __restrict__ Ml,
    const float* __restrict__ Init,
    const float* In,
    float* OutEach,
    float* __restrict__ OutFinal,
    int nupd, int gstride, int nseq, int init_bcast, int entry_mode) {
  const int seq0 = blockIdx.x * 2;
  const int tid  = threadIdx.x;
  const int lane = tid & 63;
  const int w    = tid >> 6;          // 16 waves, state-col tile w
  const int br   = lane & 15;         // batch row 0..15
  const int akg  = lane >> 4;

  __shared__ fp16_t hH[2][8 * 512];   // [buf][slice-linear 8KB]
  __shared__ fp16_t hL[2][8 * 512];

  // init h (buf 0), slice-linear
  {
    const int task = tid >> 1;        // 0..511
    const int half = tid & 1;
    const int row  = task & 15;
    const int s    = (task >> 4) & 7;
    const int ak   = task >> 7;       // 0..3
    const int sq = seq0 + (row >> 3);
    const int b  = row & 7;
    const int c0 = s * 32 + ak * 8 + half * 4;
    f32x4 v = (f32x4)0.0f;
    if (Init != nullptr && sq < nseq) {
      const size_t off = init_bcast ? (size_t)c0
                                    : ((size_t)sq * NBATCH + b) * ND + c0;
      v = *(const f32x4*)&Init[off];
      if (entry_mode && OutEach != nullptr)
        *(f32x4*)&OutEach[((size_t)sq * gstride * NBATCH + b) * ND + c0] = v;
    }
    f16x4 vh, vl;
    #pragma unroll
    for (int j = 0; j < 4; ++j) {
      const fp16_t h = (fp16_t)v[j];
      vh[j] = h;
      vl[j] = (fp16_t)((v[j] - (float)h) * LOSC);
    }
    const int off = (s << 10) + ((((ak << 4) | row) ^ s) << 4) + half * 8;
    *(f16x4*)((char*)hH[0] + off) = vh;
    *(f16x4*)((char*)hL[0] + off) = vl;
  }

  // A^T frags (A-operand) for this wave's state-col tile (L2-resident reloads)
  f16x8 AH[8], AL[8];
  #pragma unroll
  for (int s = 0; s < 8; ++s) {
    const size_t fo = (((size_t)w * 8 + s) * 64 + lane) * 8;
    AH[s] = *(const f16x8*)&Mh[fo];
    AL[s] = *(const f16x8*)&Ml[fo];
  }
  __syncthreads();

  // this lane's output: batch-row br -> (seq, b); 4 consecutive state cols
  const int sq   = seq0 + (br >> 3);
  const int b    = br & 7;
  const bool live = (sq < nseq);
  const int sqc  = live ? sq : (nseq - 1);     // clamp for safe loads
  const int col0 = w * 16 + akg * 4;

  // precomputed LDS offsets
  int rdoff[8];
  #pragma unroll
  for (int s = 0; s < 8; ++s)
    rdoff[s] = (s << 10) + ((((akg << 4) | br) ^ s) << 4);
  const int sw   = col0 >> 5;
  const int akr  = (col0 >> 3) & 3;
  const int wroff = (sw << 10) + ((((akr << 4) | br) ^ sw) << 4) + (col0 & 7) * 2;

  f32x4 uv = *(const f32x4*)&In[((size_t)(sqc * gstride) * NBATCH + b) * ND + col0];
  f32x4 uvn;
  f32x4 res;
  int p = 0;
  for (int j = 0; j < nupd; ++j) {
    if (j + 1 < nupd)
      uvn = *(const f32x4*)&In[((size_t)(sqc * gstride + j + 1) * NBATCH + b) * ND + col0];
    const char* rH = (const char*)hH[p];
    const char* rL = (const char*)hL[p];
    f32x4 accm = uv, acclA = (f32x4)0.0f, acclB = (f32x4)0.0f;
    #pragma unroll
    for (int s = 0; s < 8; ++s) {
      const f16x8 bh = *(const f16x8*)(rH + rdoff[s]);
      const f16x8 bl = *(const f16x8*)(rL + rdoff[s]);
      accm  = __builtin_amdgcn_mfma_f32_16x16x32_f16(AH[s], bh, accm,  0, 0, 0);
      acclA = __builtin_amdgcn_mfma_f32_16x16x32_f16(AL[s], bh, acclA, 0, 0, 0);
      acclB = __builtin_amdgcn_mfma_f32_16x16x32_f16(AH[s], bl, acclB, 0, 0, 0);
    }
    #pragma unroll
    for (int r = 0; r < 4; ++r) res[r] = accm[r] + (acclA[r] + acclB[r]) * LOINV;
    // write new h into the OTHER buffer (no barrier needed before writes)
    {
      f16x4 vh, vl;
      #pragma unroll
      for (int r = 0; r < 4; ++r) {
        const fp16_t hh = (fp16_t)res[r];
        vh[r] = hh;
        vl[r] = (fp16_t)((res[r] - (float)hh) * LOSC);
      }
      *(f16x4*)((char*)hH[p ^ 1] + wroff) = vh;
      *(f16x4*)((char*)hL[p ^ 1] + wroff) = vl;
    }
    if (OutEach != nullptr && live) {
      const size_t pos = entry_mode ? (size_t)(sq * gstride + j + 1)
                                    : (size_t)(sq * gstride + j);
      *(f32x4*)&OutEach[(pos * NBATCH + b) * ND + col0] = res;
    }
    uv = uvn;
    p ^= 1;
    __syncthreads();                  // new h visible; old buf free for reuse
  }

  if (OutFinal != nullptr && live)
    *(f32x4*)&OutFinal[((size_t)sq * NBATCH + b) * ND + col0] = res;
}

// ---------- dense 256x256 f32 GEMM (A-power chain) ----------
__global__ __launch_bounds__(256) void gemm256(const float* __restrict__ X,
                                               const float* __restrict__ Y,
                                               float* __restrict__ Out) {
  const int m0 = blockIdx.x * 4;
  const int n  = threadIdx.x;
  __shared__ float Xs[ND][4];
  #pragma unroll
  for (int r = 0; r < 4; ++r) Xs[n][r] = X[(m0 + r) * ND + n];
  __syncthreads();
  float a0 = 0.f, a1 = 0.f, a2 = 0.f, a3 = 0.f;
  #pragma unroll 8
  for (int k = 0; k < ND; ++k) {
    const float yv = Y[k * ND + n];
    const float4 xv = *(const float4*)&Xs[k][0];
    a0 = fmaf(xv.x, yv, a0);
    a1 = fmaf(xv.y, yv, a1);
    a2 = fmaf(xv.z, yv, a2);
    a3 = fmaf(xv.w, yv, a3);
  }
  Out[(m0 + 0) * ND + n] = a0;
  Out[(m0 + 1) * ND + n] = a1;
  Out[(m0 + 2) * ND + n] = a2;
  Out[(m0 + 3) * ND + n] = a3;
}

extern "C" void kernel_launch(void* const* d_in, const int* in_sizes, int n_in,
                              void* d_out, int out_size, void* d_ws, size_t ws_size,
                              hipStream_t stream) {
  const float* x  = (const float*)d_in[0];
  const float* A  = (const float*)d_in[1];
  const float* Bm = (const float*)d_in[2];
  const float* Cm = (const float*)d_in[3];
  const float* h0 = (const float*)d_in[4];
  float* y = (float*)d_out;

  float* U     = (float*)d_ws;                        // 8,388,608
  float* t0    = U + (size_t)SEQ * NBATCH * ND;       // 65,536 squaring scratch
  float* t1    = t0 + ND * ND;                        // 65,536
  float* A8f   = t1 + ND * ND;                        // 65,536
  float* A64f  = A8f + ND * ND;                       // 65,536
  float* A512f = A64f + ND * ND;                      // 65,536
  float* E     = A512f + ND * ND;                     // 1,048,576  [512][8][256]
  float* S1    = E + (size_t)NCHUNK * NBATCH * ND;    // 131,072    [64][8][256]
  float* S2    = S1 + (size_t)64 * NBATCH * ND;       // 16,384     [8][8][256]
  float* G3    = S2 + (size_t)8 * NBATCH * ND;        // 16,384     [8][8][256]
  float* Hc2   = G3 + (size_t)8 * NBATCH * ND;        // 131,072    [64][8][256]
  float* Hc    = Hc2 + (size_t)64 * NBATCH * ND;      // 1,048,576  [512][8][256]
  fp16_t* fA_hi   = (fp16_t*)(Hc + (size_t)NCHUNK * NBATCH * ND);
  fp16_t* fA_lo   = fA_hi + ND * ND;
  fp16_t* fB_hi   = fA_lo + ND * ND;
  fp16_t* fB_lo   = fB_hi + ND * ND;
  fp16_t* fC_hi   = fB_lo + ND * ND;
  fp16_t* fC_lo   = fC_hi + ND * ND;
  fp16_t* fA8_hi  = fC_lo + ND * ND;
  fp16_t* fA8_lo  = fA8_hi + ND * ND;
  fp16_t* fA64_hi = fA8_lo + ND * ND;
  fp16_t* fA64_lo = fA64_hi + ND * ND;
  fp16_t* fA512_hi = fA64_lo + ND * ND;
  fp16_t* fA512_lo = fA512_hi + ND * ND;

  // pack A,B,C into fragment arrays
  prep_frags3<<<384, 64, 0, stream>>>(A, Bm, Cm, fA_hi, fA_lo, fB_hi, fB_lo,
                                      fC_hi, fC_lo);

  // A powers (f32): A^8, A^64, A^512 by repeated squaring
  gemm256<<<64, 256, 0, stream>>>(A,    A,    t0);     // A^2
  gemm256<<<64, 256, 0, stream>>>(t0,   t0,   t1);     // A^4
  gemm256<<<64, 256, 0, stream>>>(t1,   t1,   A8f);    // A^8
  gemm256<<<64, 256, 0, stream>>>(A8f,  A8f,  t0);     // A^16
  gemm256<<<64, 256, 0, stream>>>(t0,   t0,   t1);     // A^32
  gemm256<<<64, 256, 0, stream>>>(t1,   t1,   A64f);   // A^64
  gemm256<<<64, 256, 0, stream>>>(A64f, A64f, t0);     // A^128
  gemm256<<<64, 256, 0, stream>>>(t0,   t0,   t1);     // A^256
  gemm256<<<64, 256, 0, stream>>>(t1,   t1,   A512f);  // A^512

  // pack A8/A64/A512 into frag arrays
  prep_frags3<<<384, 64, 0, stream>>>(A8f, A64f, A512f,
                                      fA8_hi, fA8_lo, fA64_hi, fA64_lo,
                                      fA512_hi, fA512_lo);

  // U = x @ B
  mfma_gemm<<<512, 1024, 0, stream>>>(x, fB_hi, fB_lo, U, 0);

  // chunk local ends: E[c] = scan(0; u over chunk c)     [256 blocks]
  mfma_rscan<<<NCHUNK / 2, 1024, 0, stream>>>(fA_hi, fA_lo, nullptr, U,
                                              nullptr, E, 8, 8, NCHUNK, 0, 0);

  // L1 collect: S1[g] = scan(0; E over group g) with A^8  [32 blocks]
  mfma_rscan<<<32, 1024, 0, stream>>>(fA8_hi, fA8_lo, nullptr, E,
                                      nullptr, S1, 8, 8, 64, 0, 0);

  // L2 collect: S2[g] = scan(0; S1 over group g) with A^64  [4 blocks]
  mfma_rscan<<<4, 1024, 0, stream>>>(fA64_hi, fA64_lo, nullptr, S1,
                                     nullptr, S2, 8, 8, 8, 0, 0);

  // top: G3[0]=h0; G3[k+1] = G3[k]@A512 + S2[k]   [1 block, 7 steps]
  mfma_rscan<<<1, 1024, 0, stream>>>(fA512_hi, fA512_lo, h0, S2,
                                     G3, nullptr, 7, 8, 1, 1, 1);

  // L2 apply: Hc2 entries for all 64 L1 groups (mult A^64)   [4 blocks]
  mfma_rscan<<<4, 1024, 0, stream>>>(fA64_hi, fA64_lo, G3, S1,
                                     Hc2, nullptr, 7, 8, 8, 0, 1);

  // L1 apply: Hc entries for all 512 chunks (mult A^8)   [32 blocks]
  mfma_rscan<<<32, 1024, 0, stream>>>(fA8_hi, fA8_lo, Hc2, E,
                                      Hc, nullptr, 7, 8, 64, 0, 1);

  // final chunk scan from true entries; h overwrites U   [256 blocks]
  mfma_rscan<<<NCHUNK / 2, 1024, 0, stream>>>(fA_hi, fA_lo, Hc, U,
                                              U, nullptr, 8, 8, NCHUNK, 0, 0);

  // y = h @ C
  mfma_gemm<<<512, 1024, 0, stream>>>(U, fC_hi, fC_lo, y, 1);
}